// Round 1
// baseline (303.652 us; speedup 1.0000x reference)
//
#include <hip/hip_runtime.h>
#include <stdint.h>

typedef unsigned short u16;
typedef unsigned int   u32;
typedef __attribute__((ext_vector_type(8))) short short8;
typedef __attribute__((ext_vector_type(4))) float f32x4;

__device__ __forceinline__ float bf2f(u16 h){
    return __uint_as_float(((u32)h) << 16);
}
__device__ __forceinline__ u16 f2bf(float f){
    u32 u = __float_as_uint(f);
    u += 0x7fffu + ((u >> 16) & 1u);   // RNE
    return (u16)(u >> 16);
}

// async global->LDS, 16B per lane. LDS dest must be wave-uniform base + lane*16.
__device__ __forceinline__ void gl_lds16(const void* g, void* l){
    __builtin_amdgcn_global_load_lds(
        (__attribute__((address_space(1))) void*)(uintptr_t)g,
        (__attribute__((address_space(3))) void*)(uintptr_t)l,
        16, 0, 0);
}

// ---- one-block probe: edge fmt + small tensors + cnt zeroing --------------
__global__ void probe_all(const u16* __restrict__ w1, const int* __restrict__ ei,
                          const void* b1, const void* b2, const void* b3,
                          const void* b4, const void* av,
                          int* __restrict__ efmt, int* __restrict__ cnt, int N,
                          u16* d1, u16* d2, u16* d3, u16* d4, u16* da){
    __shared__ int sf32, sfmt;
    int t = threadIdx.x;                 // 256
    if (t == 0){ sf32 = 0; sfmt = 0; }
    __syncthreads();
    for (int i = t; i < N; i += 256) cnt[i] = 0;
    {   // fp32-vs-bf16 probe on W1 (~N(0,0.02)): bf16 never has |v|>=1
        int huge = 0;
        #pragma unroll
        for (int k = 0; k < 16; k++){
            u16 h = w1[t * 16 + k];
            if (((h >> 7) & 0xFF) >= 0x7F) huge = 1;
        }
        if (huge) atomicOr(&sf32, 1);
    }
    if (ei[2*t + 1] != 0) atomicOr(&sfmt, 1);   // int64 => odd words zero
    __syncthreads();
    int f32 = sf32;
    if (t == 0) efmt[0] = sfmt;
    #define CV(s,i) (f32 ? f2bf(((const float*)(s))[i]) : ((const u16*)(s))[i])
    d1[t]       = CV(b1, t);
    d1[t + 256] = CV(b1, t + 256);
    d2[t] = CV(b2, t);
    d3[t] = CV(b3, t);
    d4[t] = CV(b4, t);
    if (t == 0) da[0] = CV(av, 0);
    #undef CV
}

// (2,E) block layout per jax: src = row0, dst = row1
__device__ __forceinline__ int eload(const int* ei, int fmt, int idx){
    return fmt ? ei[idx] : ei[2*idx];    // int64 little-endian: low word
}

// ---------------- degree / CSR build (dst-keyed) ---------------------------
__global__ void deg_count(const int* __restrict__ ei, const int* __restrict__ efmt,
                          int* __restrict__ cnt, int E, int N){
    int e = blockIdx.x * 256 + threadIdx.x;
    if (e < E){
        int d = eload(ei, efmt[0], E + e);
        if ((unsigned)d < (unsigned)N) atomicAdd(&cnt[d], 1);
    }
}

__global__ void scan1(const int* __restrict__ cnt, int* __restrict__ incl,
                      int* __restrict__ bsum, int N){
    __shared__ int s[256];
    int t = threadIdx.x, i = blockIdx.x * 256 + t;
    int v = (i < N) ? cnt[i] : 0;
    s[t] = v;
    __syncthreads();
    #pragma unroll
    for (int off = 1; off < 256; off <<= 1){
        int u = (t >= off) ? s[t - off] : 0;
        __syncthreads();
        s[t] += u;
        __syncthreads();
    }
    if (i < N) incl[i] = s[t];
    if (t == 255) bsum[blockIdx.x] = s[255];
}

// merged scan2+scan3: each block redundantly scans the <=128 block sums
__global__ void scan23(const int* __restrict__ cnt, const int* __restrict__ incl,
                       const int* __restrict__ bsum, int nb,
                       int* __restrict__ rowstart, int* __restrict__ cursor,
                       float* __restrict__ dis, int N){
    __shared__ int s[128];
    int t = threadIdx.x;   // 256
    if (t < 128) s[t] = (t < nb) ? bsum[t] : 0;
    __syncthreads();
    #pragma unroll
    for (int off = 1; off < 128; off <<= 1){
        int u = 0;
        if (t < 128 && t >= off) u = s[t - off];
        __syncthreads();
        if (t < 128) s[t] += u;
        __syncthreads();
    }
    int boffb = s[blockIdx.x] - bsum[blockIdx.x];   // exclusive prefix for this block
    int i = blockIdx.x * 256 + t;
    if (i < N){
        int v = cnt[i];
        int rsv = boffb + incl[i] - v;
        rowstart[i] = rsv;
        cursor[i]   = rsv;
        dis[i] = rsqrtf((float)v + 1.0f);
    }
    if (blockIdx.x == 0 && t == 0) rowstart[N] = s[nb - 1];
}

__global__ void csr_fill(const int* __restrict__ ei, const int* __restrict__ efmt,
                         int* __restrict__ cursor, int* __restrict__ csr_src,
                         int E, int N){
    int e = blockIdx.x * 256 + threadIdx.x;
    if (e < E){
        int fmt = efmt[0];
        int d = eload(ei, fmt, E + e);
        if ((unsigned)d < (unsigned)N){
            int p = atomicAdd(&cursor[d], 1);
            csr_src[p] = eload(ei, fmt, e);
        }
    }
}

// -------- weights: convert+transpose + X->bf16 cast in ONE launch ----------
// z=0..3: 32x32 transpose tiles of W1..W4 ; z=4: grid-stride X cast.
// Each block self-probes fp32-vs-bf16 from W1 (no dependency on probe_all).
__global__ void transpose_x(const void* w1, const void* w2, const void* w3,
                            const void* w4, const void* X,
                            u16* o1, u16* o2, u16* o3, u16* o4,
                            u16* xbf, int NN){
    __shared__ int sf;
    __shared__ u16 tb[32][33];
    int lt = threadIdx.y * 32 + threadIdx.x;   // 0..255
    if (lt == 0) sf = 0;
    __syncthreads();
    {   // self-probe: fp32 stream read as u16 has random mantissa-low words
        int huge = 0;
        const u16* w = (const u16*)w1;
        #pragma unroll
        for (int k = 0; k < 8; k++){
            u16 h = w[lt * 8 + k];
            if (((h >> 7) & 0xFF) >= 0x7F) huge = 1;
        }
        if (huge) atomicOr(&sf, 1);
    }
    __syncthreads();
    int f32 = sf;

    if (blockIdx.z == 4){   // X cast: NN*512 bf16 elems, short8 groups
        size_t nb8 = (size_t)NN * 64;
        size_t step = 256u * 256u;   // 256 blocks x 256 threads
        for (size_t i = (size_t)(blockIdx.y * 16 + blockIdx.x) * 256 + lt; i < nb8; i += step){
            short8 o;
            if (f32){
                const float* p = (const float*)X + i * 8;
                f32x4 a0 = *(const f32x4*)p;
                f32x4 a1 = *(const f32x4*)(p + 4);
                #pragma unroll
                for (int j = 0; j < 4; j++){
                    o[j]     = (short)f2bf(a0[j]);
                    o[4 + j] = (short)f2bf(a1[j]);
                }
            } else {
                o = *(const short8*)((const u16*)X + i * 8);
            }
            *(short8*)(xbf + i * 8) = o;
        }
        return;
    }

    const void* in; u16* out; int K, N;
    switch (blockIdx.z){
        case 0:  in = w1; out = o1; K = 512; N = 512; break;
        case 1:  in = w2; out = o2; K = 512; N = 256; break;
        case 2:  in = w3; out = o3; K = 256; N = 256; break;
        default: in = w4; out = o4; K = 256; N = 256; break;
    }
    int bx = blockIdx.x * 32;   // n
    int by = blockIdx.y * 32;   // k
    if (bx >= N || by >= K) return;
    int x = threadIdx.x, y = threadIdx.y;   // (32,8)
    #pragma unroll
    for (int i = 0; i < 32; i += 8){
        size_t idx = (size_t)(by + y + i) * N + bx + x;
        tb[y + i][x] = f32 ? f2bf(((const float*)in)[idx]) : ((const u16*)in)[idx];
    }
    __syncthreads();
    #pragma unroll
    for (int i = 0; i < 32; i += 8)
        out[(size_t)(bx + y + i) * K + by + x] = tb[x][y + i];
}

// ---------------- MFMA GEMM (m97 structure) --------------------------------
// C[M][N] = A[M][K] * BT[N][K]^T. 128x128 tile, BK=64, 256 thr = 4 waves (2x2),
// each wave 64x64 = 4x4 16x16 frags. Staging via global_load_lds dwordx4.
#define GTM 128
#define GTN 128
#define GBK 64

template<int MODE, int OUTF>   // MODE: 0 plain,1 +bias,2 +bias+ELU; OUTF: 0 bf16,1 fp32
__global__ __launch_bounds__(256) void gemm128(
    const u16* __restrict__ A, const u16* __restrict__ BT,
    const u16* __restrict__ bias, void* __restrict__ Cv,
    int M, int K, int N)
{
    __shared__ __align__(16) u16 As[GTM * GBK];   // 16 KB, linear [128][64]
    __shared__ __align__(16) u16 Bs[GTN * GBK];   // 16 KB
    int tid  = threadIdx.x;
    int lane = tid & 63;
    int wm   = (tid >> 7) & 1;
    int wn   = (tid >> 6) & 1;
    int bm = blockIdx.x * GTM;
    int bn = blockIdx.y * GTN;

    f32x4 acc[4][4] = {};

    // staging: round r covers rows r*32..r*32+31; thread -> (row tid>>3, col (tid&7)*8)
    // LDS dest byte offset = tid*16 + r*4096  (linear in lane order per wave)
    int srow = tid >> 3;
    int scol = (tid & 7) * 8;
    const u16* aP = A  + (size_t)(bm + srow) * K + scol;
    const u16* bP = BT + (size_t)(bn + srow) * K + scol;
    u16* lA = &As[tid * 8];
    u16* lB = &Bs[tid * 8];

    int q   = lane >> 4;
    int r16 = lane & 15;
    const u16* ra = &As[(wm*64 + r16) * GBK + q*8];
    const u16* rb = &Bs[(wn*64 + r16) * GBK + q*8];

    for (int k0 = 0; k0 < K; k0 += GBK){
        #pragma unroll
        for (int r = 0; r < 4; r++){
            gl_lds16(aP + (size_t)r*32*K + k0, lA + r*32*GBK);
            gl_lds16(bP + (size_t)r*32*K + k0, lB + r*32*GBK);
        }
        __syncthreads();   // vmcnt drain + barrier: tile ready
        #pragma unroll
        for (int kk = 0; kk < 2; kk++){
            short8 af[4], bf[4];
            #pragma unroll
            for (int i = 0; i < 4; i++) af[i] = *(const short8*)(ra + i*16*GBK + kk*32);
            #pragma unroll
            for (int j = 0; j < 4; j++) bf[j] = *(const short8*)(rb + j*16*GBK + kk*32);
            #pragma unroll
            for (int i = 0; i < 4; i++)
                #pragma unroll
                for (int j = 0; j < 4; j++)
                    acc[i][j] = __builtin_amdgcn_mfma_f32_16x16x32_bf16(af[i], bf[j], acc[i][j], 0, 0, 0);
        }
        __syncthreads();   // protect LDS before next overwrite
    }

    int q4 = q * 4;
    #pragma unroll
    for (int i = 0; i < 4; i++){
        #pragma unroll
        for (int j = 0; j < 4; j++){
            int gcol = bn + wn*64 + j*16 + r16;
            float bvv = (MODE >= 1) ? bf2f(bias[gcol]) : 0.f;
            #pragma unroll
            for (int r = 0; r < 4; r++){
                int grow = bm + wm*64 + i*16 + q4 + r;
                if (grow < M){
                    float v = acc[i][j][r] + bvv;
                    if (MODE == 2) v = (v > 0.f) ? v : expm1f(v);
                    if (OUTF) ((float*)Cv)[(size_t)grow * N + gcol] = v;
                    else      ((u16*)Cv)[(size_t)grow * N + gcol] = f2bf(v);
                }
            }
        }
    }
}

// ---------------- pull aggregation (+bias+PReLU), F features ---------------
// Static blocked layout; 8-edge groups with SW-pipelined index prefetch.
// out = prelu( di*( sum_e dis[s_e]*row_e + di*row_self ) + bias )
template<int F, int NPB>
__global__ __launch_bounds__(F/8*NPB) void aggregate(
    const u16* __restrict__ XW, const int* __restrict__ rowstart,
    const int* __restrict__ csr_src, const float* __restrict__ dis,
    const u16* __restrict__ bias, const u16* __restrict__ aptr,
    u16* __restrict__ out, int N)
{
    int node = blockIdx.x * NPB + threadIdx.y;
    if (node >= N) return;
    int tf = threadIdx.x * 8;
    float a  = bf2f(aptr[0]);
    float di = dis[node];
    int e0 = rowstart[node], e1 = rowstart[node + 1];
    float acc[8] = {0,0,0,0,0,0,0,0};
    int ng = (e1 - e0) >> 3;
    int si[8]; float ci[8];
    if (ng > 0){
        #pragma unroll
        for (int u = 0; u < 8; u++) si[u] = csr_src[e0 + u];
        #pragma unroll
        for (int u = 0; u < 8; u++) ci[u] = dis[si[u]];
    }
    for (int g = 0; g < ng; g++){
        short8 vi[8];
        #pragma unroll
        for (int u = 0; u < 8; u++)
            vi[u] = *(const short8*)(XW + (size_t)si[u] * F + tf);
        int sn[8]; float cn[8];
        bool more = (g + 1) < ng;
        if (more){   // prefetch next group's indices+coeffs while rows in flight
            int base = e0 + (g + 1) * 8;
            #pragma unroll
            for (int u = 0; u < 8; u++) sn[u] = csr_src[base + u];
            #pragma unroll
            for (int u = 0; u < 8; u++) cn[u] = dis[sn[u]];
        }
        #pragma unroll
        for (int u = 0; u < 8; u++)
            #pragma unroll
            for (int j = 0; j < 8; j++)
                acc[j] += ci[u] * bf2f((u16)vi[u][j]);
        if (more){
            #pragma unroll
            for (int u = 0; u < 8; u++){ si[u] = sn[u]; ci[u] = cn[u]; }
        }
    }
    int e = e0 + ng * 8;
    for (; e + 4 <= e1; e += 4){
        int s0 = csr_src[e], s1 = csr_src[e+1], s2 = csr_src[e+2], s3 = csr_src[e+3];
        float c0 = dis[s0], c1 = dis[s1], c2 = dis[s2], c3 = dis[s3];
        short8 v0 = *(const short8*)(XW + (size_t)s0 * F + tf);
        short8 v1 = *(const short8*)(XW + (size_t)s1 * F + tf);
        short8 v2 = *(const short8*)(XW + (size_t)s2 * F + tf);
        short8 v3 = *(const short8*)(XW + (size_t)s3 * F + tf);
        #pragma unroll
        for (int j = 0; j < 8; j++)
            acc[j] += c0*bf2f((u16)v0[j]) + c1*bf2f((u16)v1[j])
                    + c2*bf2f((u16)v2[j]) + c3*bf2f((u16)v3[j]);
    }
    for (; e < e1; e++){
        int s = csr_src[e];
        float c = dis[s];
        short8 v = *(const short8*)(XW + (size_t)s * F + tf);
        #pragma unroll
        for (int j = 0; j < 8; j++) acc[j] += c * bf2f((u16)v[j]);
    }
    {   // self-loop
        short8 v = *(const short8*)(XW + (size_t)node * F + tf);
        #pragma unroll
        for (int j = 0; j < 8; j++) acc[j] += di * bf2f((u16)v[j]);
    }
    short8 bv = *(const short8*)(bias + tf);
    short8 o;
    #pragma unroll
    for (int j = 0; j < 8; j++){
        float x = di * acc[j] + bf2f((u16)bv[j]);
        x = (x > 0.f) ? x : a * x;
        o[j] = (short)f2bf(x);
    }
    *(short8*)(out + (size_t)node * F + tf) = o;
}

// ---------------- launch ----------------------------------------------------
extern "C" void kernel_launch(void* const* d_in, const int* in_sizes, int n_in,
                              void* d_out, int out_size, void* d_ws, size_t ws_size,
                              hipStream_t stream)
{
    int iX=0, iEI=1, iW1=2, ib1=3, iW2=4, ib2=5, ia=6, iW3=7, ib3=8, iW4=9, ib4=10;
    {
        int jX=-1,jEI=-1,jW1=-1,jb1=-1,jW2=-1,ja=-1,jW3=-1,jW4=-1,jb2=-1,jb3=-1,jb4=-1;
        int n64k=0, n256=0;
        for (int i = 0; i < n_in; i++){
            switch (in_sizes[i]){
                case 10240000: jX = i; break;
                case 640000:   jEI = i; break;
                case 262144:   jW1 = i; break;
                case 131072:   jW2 = i; break;
                case 512:      jb1 = i; break;
                case 1:        ja = i; break;
                case 65536:    if (n64k++ == 0) jW3 = i; else jW4 = i; break;
                case 256: {
                    int k = n256++;
                    if (k == 0) jb2 = i; else if (k == 1) jb3 = i; else jb4 = i;
                } break;
                default: break;
            }
        }
        if (jX>=0&&jEI>=0&&jW1>=0&&jb1>=0&&jW2>=0&&ja>=0&&jW3>=0&&jW4>=0&&jb2>=0&&jb3>=0&&jb4>=0){
            iX=jX; iEI=jEI; iW1=jW1; ib1=jb1; iW2=jW2; ib2=jb2; ia=ja; iW3=jW3; ib3=jb3; iW4=jW4; ib4=jb4;
        }
    }
    int N = in_sizes[iX] / 512;
    int E = in_sizes[iEI] / 2;
    const int* EI = (const int*)d_in[iEI];
    float* OUT = (float*)d_out;                 // fp32 output (N*256*4 bytes)
    u16*   S   = (u16*)d_out;                   // same bytes as bf16 N x 512 scratch

    char* ws = (char*)d_ws;
    size_t off = 0;
    auto alloc = [&](size_t bytes)->char*{
        char* p = ws + off;
        off = (off + bytes + 255) & ~(size_t)255;
        return p;
    };
    int nb = (N + 255) / 256;                   // scan blocks (N<=32768)
    int MP = N + 128;                           // row-padded for OOB tile staging
    int*   cnt  = (int*)  alloc((size_t)N*4);
    int*   incl = (int*)  alloc((size_t)N*4);
    int*   bsum = (int*)  alloc(512);
    int*   efmt = (int*)  alloc(4);
    float* dis  = (float*)alloc((size_t)N*4);
    int*   rs   = (int*)  alloc((size_t)(N+1)*4);
    int*   cur  = (int*)  alloc((size_t)N*4);
    int*   csr  = (int*)  alloc((size_t)E*4);
    u16*   WT1  = (u16*)  alloc((size_t)512*512*2);
    u16*   WT2  = (u16*)  alloc((size_t)256*512*2);
    u16*   WT3  = (u16*)  alloc((size_t)256*256*2);
    u16*   WT4  = (u16*)  alloc((size_t)256*256*2);
    u16*   b1c  = (u16*)  alloc((size_t)512*2);
    u16*   b2c  = (u16*)  alloc((size_t)256*2);
    u16*   b3c  = (u16*)  alloc((size_t)256*2);
    u16*   b4c  = (u16*)  alloc((size_t)256*2);
    u16*   ac   = (u16*)  alloc((size_t)8*2);
    u16*   Xbf  = (u16*)  alloc((size_t)MP*512*2);  // 20.6 MB
    u16*   h1   = (u16*)  alloc((size_t)MP*512*2);  // 20.6 MB
    u16*   P    = (u16*)  alloc((size_t)MP*256*2);  // 10.3 MB

    if (ws_size < off) return;

    probe_all<<<1, 256, 0, stream>>>((const u16*)d_in[iW1], EI,
                                     d_in[ib1], d_in[ib2], d_in[ib3], d_in[ib4],
                                     d_in[ia], efmt, cnt, N,
                                     b1c, b2c, b3c, b4c, ac);

    transpose_x<<<dim3(16, 16, 5), dim3(32, 8), 0, stream>>>(
        d_in[iW1], d_in[iW2], d_in[iW3], d_in[iW4], d_in[iX],
        WT1, WT2, WT3, WT4, Xbf, N);

    int egrid = (E + 255) / 256;
    deg_count<<<egrid, 256, 0, stream>>>(EI, efmt, cnt, E, N);
    scan1<<<nb, 256, 0, stream>>>(cnt, incl, bsum, N);
    scan23<<<nb, 256, 0, stream>>>(cnt, incl, bsum, nb, rs, cur, dis, N);
    csr_fill<<<egrid, 256, 0, stream>>>(EI, efmt, cur, csr, E, N);

    int gm = (N + GTM - 1) / GTM;         // 157
    dim3 g512(gm, 512 / GTN);             // 628 blocks
    dim3 g256(gm, 256 / GTN);             // 314 blocks

    // layer 1: Xbf @ W1 -> S (bf16 scratch in OUT buffer), aggregate -> h1
    gemm128<0,0><<<g512, 256, 0, stream>>>(Xbf, WT1, nullptr, S, N, 512, 512);
    aggregate<512,8><<<(N+7)/8, dim3(64,8), 0, stream>>>(S, rs, csr, dis, b1c, ac, h1, N);

    // layer 2: h1 @ W2 -> P ; aggregate -> Q (OUT bytes as bf16; S dead)
    u16* Q = (u16*)d_out;
    gemm128<0,0><<<g256, 256, 0, stream>>>(h1, WT2, nullptr, P, N, 512, 256);
    aggregate<256,16><<<(N+15)/16, dim3(32,16), 0, stream>>>(P, rs, csr, dis, b2c, ac, Q, N);

    // projection MLP: ELU(Q @ W3 + b3) -> P ; P @ W4 + b4 -> OUT (fp32)
    gemm128<2,0><<<g256, 256, 0, stream>>>(Q, WT3, b3c, P, N, 256, 256);
    gemm128<1,1><<<g256, 256, 0, stream>>>(P, WT4, b4c, OUT, N, 256, 256);
}

// Round 2
// 296.951 us; speedup vs baseline: 1.0226x; 1.0226x over previous
//
#include <hip/hip_runtime.h>
#include <stdint.h>

typedef unsigned short u16;
typedef unsigned int   u32;
typedef __attribute__((ext_vector_type(8))) short short8;
typedef __attribute__((ext_vector_type(4))) float f32x4;

__device__ __forceinline__ float bf2f(u16 h){
    return __uint_as_float(((u32)h) << 16);
}
__device__ __forceinline__ u16 f2bf(float f){
    u32 u = __float_as_uint(f);
    u += 0x7fffu + ((u >> 16) & 1u);   // RNE
    return (u16)(u >> 16);
}

// async global->LDS, 16B per lane. LDS dest must be wave-uniform base + lane*16.
__device__ __forceinline__ void gl_lds16(const void* g, void* l){
    __builtin_amdgcn_global_load_lds(
        (__attribute__((address_space(1))) void*)(uintptr_t)g,
        (__attribute__((address_space(3))) void*)(uintptr_t)l,
        16, 0, 0);
}

// ---- one-block probe: edge fmt + small tensors + cnt zeroing --------------
__global__ void probe_all(const u16* __restrict__ w1, const int* __restrict__ ei,
                          const void* b1, const void* b2, const void* b3,
                          const void* b4, const void* av,
                          int* __restrict__ efmt, int* __restrict__ cnt, int N,
                          u16* d1, u16* d2, u16* d3, u16* d4, u16* da){
    __shared__ int sf32, sfmt;
    int t = threadIdx.x;                 // 256
    if (t == 0){ sf32 = 0; sfmt = 0; }
    __syncthreads();
    for (int i = t; i < N; i += 256) cnt[i] = 0;
    {   // fp32-vs-bf16 probe on W1 (~N(0,0.02)): bf16 never has |v|>=1
        int huge = 0;
        #pragma unroll
        for (int k = 0; k < 16; k++){
            u16 h = w1[t * 16 + k];
            if (((h >> 7) & 0xFF) >= 0x7F) huge = 1;
        }
        if (huge) atomicOr(&sf32, 1);
    }
    if (ei[2*t + 1] != 0) atomicOr(&sfmt, 1);   // int64 => odd words zero
    __syncthreads();
    int f32 = sf32;
    if (t == 0) efmt[0] = sfmt;
    #define CV(s,i) (f32 ? f2bf(((const float*)(s))[i]) : ((const u16*)(s))[i])
    d1[t]       = CV(b1, t);
    d1[t + 256] = CV(b1, t + 256);
    d2[t] = CV(b2, t);
    d3[t] = CV(b3, t);
    d4[t] = CV(b4, t);
    if (t == 0) da[0] = CV(av, 0);
    #undef CV
}

// (2,E) block layout per jax: src = row0, dst = row1
__device__ __forceinline__ int eload(const int* ei, int fmt, int idx){
    return fmt ? ei[idx] : ei[2*idx];    // int64 little-endian: low word
}

// ---------------- degree / CSR build (dst-keyed) ---------------------------
__global__ void deg_count(const int* __restrict__ ei, const int* __restrict__ efmt,
                          int* __restrict__ cnt, int E, int N){
    int e = blockIdx.x * 256 + threadIdx.x;
    if (e < E){
        int d = eload(ei, efmt[0], E + e);
        if ((unsigned)d < (unsigned)N) atomicAdd(&cnt[d], 1);
    }
}

__global__ void scan1(const int* __restrict__ cnt, int* __restrict__ incl,
                      int* __restrict__ bsum, int N){
    __shared__ int s[256];
    int t = threadIdx.x, i = blockIdx.x * 256 + t;
    int v = (i < N) ? cnt[i] : 0;
    s[t] = v;
    __syncthreads();
    #pragma unroll
    for (int off = 1; off < 256; off <<= 1){
        int u = (t >= off) ? s[t - off] : 0;
        __syncthreads();
        s[t] += u;
        __syncthreads();
    }
    if (i < N) incl[i] = s[t];
    if (t == 255) bsum[blockIdx.x] = s[255];
}

// merged scan2+scan3: each block redundantly scans the <=128 block sums
__global__ void scan23(const int* __restrict__ cnt, const int* __restrict__ incl,
                       const int* __restrict__ bsum, int nb,
                       int* __restrict__ rowstart, int* __restrict__ cursor,
                       float* __restrict__ dis, int N){
    __shared__ int s[128];
    int t = threadIdx.x;   // 256
    if (t < 128) s[t] = (t < nb) ? bsum[t] : 0;
    __syncthreads();
    #pragma unroll
    for (int off = 1; off < 128; off <<= 1){
        int u = 0;
        if (t < 128 && t >= off) u = s[t - off];
        __syncthreads();
        if (t < 128) s[t] += u;
        __syncthreads();
    }
    int boffb = s[blockIdx.x] - bsum[blockIdx.x];   // exclusive prefix for this block
    int i = blockIdx.x * 256 + t;
    if (i < N){
        int v = cnt[i];
        int rsv = boffb + incl[i] - v;
        rowstart[i] = rsv;
        cursor[i]   = rsv;
        dis[i] = rsqrtf((float)v + 1.0f);
    }
    if (blockIdx.x == 0 && t == 0) rowstart[N] = s[nb - 1];
}

__global__ void csr_fill(const int* __restrict__ ei, const int* __restrict__ efmt,
                         int* __restrict__ cursor, int* __restrict__ csr_src,
                         int E, int N){
    int e = blockIdx.x * 256 + threadIdx.x;
    if (e < E){
        int fmt = efmt[0];
        int d = eload(ei, fmt, E + e);
        if ((unsigned)d < (unsigned)N){
            int p = atomicAdd(&cursor[d], 1);
            csr_src[p] = eload(ei, fmt, e);
        }
    }
}

// -------- weights: convert+transpose + X->bf16 cast in ONE launch ----------
// z=0..3: 32x32 transpose tiles of W1..W4 ; z=4: grid-stride X cast.
// Each block self-probes fp32-vs-bf16 from W1 (no dependency on probe_all).
__global__ void transpose_x(const void* w1, const void* w2, const void* w3,
                            const void* w4, const void* X,
                            u16* o1, u16* o2, u16* o3, u16* o4,
                            u16* xbf, int NN){
    __shared__ int sf;
    __shared__ u16 tb[32][33];
    int lt = threadIdx.y * 32 + threadIdx.x;   // 0..255
    if (lt == 0) sf = 0;
    __syncthreads();
    {   // self-probe: fp32 stream read as u16 has random mantissa-low words
        int huge = 0;
        const u16* w = (const u16*)w1;
        #pragma unroll
        for (int k = 0; k < 8; k++){
            u16 h = w[lt * 8 + k];
            if (((h >> 7) & 0xFF) >= 0x7F) huge = 1;
        }
        if (huge) atomicOr(&sf, 1);
    }
    __syncthreads();
    int f32 = sf;

    if (blockIdx.z == 4){   // X cast: NN*512 bf16 elems, short8 groups
        size_t nb8 = (size_t)NN * 64;
        size_t step = 256u * 256u;   // 256 blocks x 256 threads
        for (size_t i = (size_t)(blockIdx.y * 16 + blockIdx.x) * 256 + lt; i < nb8; i += step){
            short8 o;
            if (f32){
                const float* p = (const float*)X + i * 8;
                f32x4 a0 = *(const f32x4*)p;
                f32x4 a1 = *(const f32x4*)(p + 4);
                #pragma unroll
                for (int j = 0; j < 4; j++){
                    o[j]     = (short)f2bf(a0[j]);
                    o[4 + j] = (short)f2bf(a1[j]);
                }
            } else {
                o = *(const short8*)((const u16*)X + i * 8);
            }
            *(short8*)(xbf + i * 8) = o;
        }
        return;
    }

    const void* in; u16* out; int K, N;
    switch (blockIdx.z){
        case 0:  in = w1; out = o1; K = 512; N = 512; break;
        case 1:  in = w2; out = o2; K = 512; N = 256; break;
        case 2:  in = w3; out = o3; K = 256; N = 256; break;
        default: in = w4; out = o4; K = 256; N = 256; break;
    }
    int bx = blockIdx.x * 32;   // n
    int by = blockIdx.y * 32;   // k
    if (bx >= N || by >= K) return;
    int x = threadIdx.x, y = threadIdx.y;   // (32,8)
    #pragma unroll
    for (int i = 0; i < 32; i += 8){
        size_t idx = (size_t)(by + y + i) * N + bx + x;
        tb[y + i][x] = f32 ? f2bf(((const float*)in)[idx]) : ((const u16*)in)[idx];
    }
    __syncthreads();
    #pragma unroll
    for (int i = 0; i < 32; i += 8)
        out[(size_t)(bx + y + i) * K + by + x] = tb[x][y + i];
}

// ---------------- MFMA GEMM (m97 structure + XCD swizzle) ------------------
// C[M][N] = A[M][K] * BT[N][K]^T. 128x128 tile, BK=64, 256 thr = 4 waves (2x2),
// each wave 64x64 = 4x4 16x16 frags. Staging via global_load_lds dwordx4.
// 1D grid; bijective XCD swizzle (m204) with n-fastest tile order so each
// XCD's contiguous tile run reuses an L2-resident A-row slice.
#define GTM 128
#define GTN 128
#define GBK 64

template<int MODE, int OUTF>   // MODE: 0 plain,1 +bias,2 +bias+ELU; OUTF: 0 bf16,1 fp32
__global__ __launch_bounds__(256) void gemm128(
    const u16* __restrict__ A, const u16* __restrict__ BT,
    const u16* __restrict__ bias, void* __restrict__ Cv,
    int M, int K, int N, int nN)
{
    __shared__ __align__(16) u16 As[GTM * GBK];   // 16 KB, linear [128][64]
    __shared__ __align__(16) u16 Bs[GTN * GBK];   // 16 KB
    int nwg = gridDim.x;
    int flat = blockIdx.x;
    int q8 = nwg >> 3, r8 = nwg & 7;
    int xcd = flat & 7, idx8 = flat >> 3;
    int wg = (xcd < r8 ? xcd * (q8 + 1) : r8 * (q8 + 1) + (xcd - r8) * q8) + idx8;
    int bm = (wg / nN) * GTM;
    int bn = (wg % nN) * GTN;

    int tid  = threadIdx.x;
    int lane = tid & 63;
    int wm   = (tid >> 7) & 1;
    int wn   = (tid >> 6) & 1;

    f32x4 acc[4][4] = {};

    int srow = tid >> 3;
    int scol = (tid & 7) * 8;
    const u16* aP = A  + (size_t)(bm + srow) * K + scol;
    const u16* bP = BT + (size_t)(bn + srow) * K + scol;
    u16* lA = &As[tid * 8];
    u16* lB = &Bs[tid * 8];

    int q   = lane >> 4;
    int r16 = lane & 15;
    const u16* ra = &As[(wm*64 + r16) * GBK + q*8];
    const u16* rb = &Bs[(wn*64 + r16) * GBK + q*8];

    for (int k0 = 0; k0 < K; k0 += GBK){
        #pragma unroll
        for (int r = 0; r < 4; r++){
            gl_lds16(aP + (size_t)r*32*K + k0, lA + r*32*GBK);
            gl_lds16(bP + (size_t)r*32*K + k0, lB + r*32*GBK);
        }
        __syncthreads();   // vmcnt drain + barrier: tile ready
        #pragma unroll
        for (int kk = 0; kk < 2; kk++){
            short8 af[4], bf[4];
            #pragma unroll
            for (int i = 0; i < 4; i++) af[i] = *(const short8*)(ra + i*16*GBK + kk*32);
            #pragma unroll
            for (int j = 0; j < 4; j++) bf[j] = *(const short8*)(rb + j*16*GBK + kk*32);
            #pragma unroll
            for (int i = 0; i < 4; i++)
                #pragma unroll
                for (int j = 0; j < 4; j++)
                    acc[i][j] = __builtin_amdgcn_mfma_f32_16x16x32_bf16(af[i], bf[j], acc[i][j], 0, 0, 0);
        }
        __syncthreads();   // protect LDS before next overwrite
    }

    int q4 = q * 4;
    #pragma unroll
    for (int i = 0; i < 4; i++){
        #pragma unroll
        for (int j = 0; j < 4; j++){
            int gcol = bn + wn*64 + j*16 + r16;
            float bvv = (MODE >= 1) ? bf2f(bias[gcol]) : 0.f;
            #pragma unroll
            for (int r = 0; r < 4; r++){
                int grow = bm + wm*64 + i*16 + q4 + r;
                if (grow < M){
                    float v = acc[i][j][r] + bvv;
                    if (MODE == 2) v = (v > 0.f) ? v : expm1f(v);
                    if (OUTF) ((float*)Cv)[(size_t)grow * N + gcol] = v;
                    else      ((u16*)Cv)[(size_t)grow * N + gcol] = f2bf(v);
                }
            }
        }
    }
}

// -------- pull aggregation, feature-chunked + XCD-pinned -------------------
// chunk = blockIdx.x % NCH -> with round-robin block->XCD mapping, XCD k only
// gathers from feature-slice k of XW (20000*64*2B = 2.56 MB, L2-resident).
// 8 lanes per node (64 feats = 8 feats/lane), 32 nodes per 256-thr block.
// out = prelu( di*( sum_e dis[s_e]*row_e + di*row_self ) + bias )
template<int F, int CH>
__global__ __launch_bounds__(256) void aggregate_ch(
    const u16* __restrict__ XW, const int* __restrict__ rowstart,
    const int* __restrict__ csr_src, const float* __restrict__ dis,
    const u16* __restrict__ bias, const u16* __restrict__ aptr,
    u16* __restrict__ out, int N)
{
    constexpr int NCH = F / CH;          // 8 (F=512) or 4 (F=256)
    constexpr int LPN = CH / 8;          // 8 lanes per node
    constexpr int NPB = 256 / LPN;       // 32 nodes per block
    int bid = blockIdx.x;
    int chunk = bid % NCH;
    int node = (bid / NCH) * NPB + (threadIdx.x >> 3);
    if (node >= N) return;
    int tf = chunk * CH + (threadIdx.x & (LPN - 1)) * 8;
    float a  = bf2f(aptr[0]);
    float di = dis[node];
    int e0 = rowstart[node], e1 = rowstart[node + 1];
    float acc[8] = {0,0,0,0,0,0,0,0};
    int ng = (e1 - e0) >> 3;
    int si[8]; float ci[8];
    if (ng > 0){
        #pragma unroll
        for (int u = 0; u < 8; u++) si[u] = csr_src[e0 + u];
        #pragma unroll
        for (int u = 0; u < 8; u++) ci[u] = dis[si[u]];
    }
    for (int g = 0; g < ng; g++){
        short8 vi[8];
        #pragma unroll
        for (int u = 0; u < 8; u++)
            vi[u] = *(const short8*)(XW + (size_t)si[u] * F + tf);
        int sn[8]; float cn[8];
        bool more = (g + 1) < ng;
        if (more){   // prefetch next group's indices+coeffs while rows in flight
            int base = e0 + (g + 1) * 8;
            #pragma unroll
            for (int u = 0; u < 8; u++) sn[u] = csr_src[base + u];
            #pragma unroll
            for (int u = 0; u < 8; u++) cn[u] = dis[sn[u]];
        }
        #pragma unroll
        for (int u = 0; u < 8; u++)
            #pragma unroll
            for (int j = 0; j < 8; j++)
                acc[j] += ci[u] * bf2f((u16)vi[u][j]);
        if (more){
            #pragma unroll
            for (int u = 0; u < 8; u++){ si[u] = sn[u]; ci[u] = cn[u]; }
        }
    }
    int e = e0 + ng * 8;
    for (; e + 4 <= e1; e += 4){
        int s0 = csr_src[e], s1 = csr_src[e+1], s2 = csr_src[e+2], s3 = csr_src[e+3];
        float c0 = dis[s0], c1 = dis[s1], c2 = dis[s2], c3 = dis[s3];
        short8 v0 = *(const short8*)(XW + (size_t)s0 * F + tf);
        short8 v1 = *(const short8*)(XW + (size_t)s1 * F + tf);
        short8 v2 = *(const short8*)(XW + (size_t)s2 * F + tf);
        short8 v3 = *(const short8*)(XW + (size_t)s3 * F + tf);
        #pragma unroll
        for (int j = 0; j < 8; j++)
            acc[j] += c0*bf2f((u16)v0[j]) + c1*bf2f((u16)v1[j])
                    + c2*bf2f((u16)v2[j]) + c3*bf2f((u16)v3[j]);
    }
    for (; e < e1; e++){
        int s = csr_src[e];
        float c = dis[s];
        short8 v = *(const short8*)(XW + (size_t)s * F + tf);
        #pragma unroll
        for (int j = 0; j < 8; j++) acc[j] += c * bf2f((u16)v[j]);
    }
    {   // self-loop
        short8 v = *(const short8*)(XW + (size_t)node * F + tf);
        #pragma unroll
        for (int j = 0; j < 8; j++) acc[j] += di * bf2f((u16)v[j]);
    }
    short8 bv = *(const short8*)(bias + tf);
    short8 o;
    #pragma unroll
    for (int j = 0; j < 8; j++){
        float x = di * acc[j] + bf2f((u16)bv[j]);
        x = (x > 0.f) ? x : a * x;
        o[j] = (short)f2bf(x);
    }
    *(short8*)(out + (size_t)node * F + tf) = o;
}

// ---------------- launch ----------------------------------------------------
extern "C" void kernel_launch(void* const* d_in, const int* in_sizes, int n_in,
                              void* d_out, int out_size, void* d_ws, size_t ws_size,
                              hipStream_t stream)
{
    int iX=0, iEI=1, iW1=2, ib1=3, iW2=4, ib2=5, ia=6, iW3=7, ib3=8, iW4=9, ib4=10;
    {
        int jX=-1,jEI=-1,jW1=-1,jb1=-1,jW2=-1,ja=-1,jW3=-1,jW4=-1,jb2=-1,jb3=-1,jb4=-1;
        int n64k=0, n256=0;
        for (int i = 0; i < n_in; i++){
            switch (in_sizes[i]){
                case 10240000: jX = i; break;
                case 640000:   jEI = i; break;
                case 262144:   jW1 = i; break;
                case 131072:   jW2 = i; break;
                case 512:      jb1 = i; break;
                case 1:        ja = i; break;
                case 65536:    if (n64k++ == 0) jW3 = i; else jW4 = i; break;
                case 256: {
                    int k = n256++;
                    if (k == 0) jb2 = i; else if (k == 1) jb3 = i; else jb4 = i;
                } break;
                default: break;
            }
        }
        if (jX>=0&&jEI>=0&&jW1>=0&&jb1>=0&&jW2>=0&&ja>=0&&jW3>=0&&jW4>=0&&jb2>=0&&jb3>=0&&jb4>=0){
            iX=jX; iEI=jEI; iW1=jW1; ib1=jb1; iW2=jW2; ib2=jb2; ia=ja; iW3=jW3; ib3=jb3; iW4=jW4; ib4=jb4;
        }
    }
    int N = in_sizes[iX] / 512;
    int E = in_sizes[iEI] / 2;
    const int* EI = (const int*)d_in[iEI];
    float* OUT = (float*)d_out;                 // fp32 output (N*256*4 bytes)
    u16*   S   = (u16*)d_out;                   // same bytes as bf16 N x 512 scratch

    char* ws = (char*)d_ws;
    size_t off = 0;
    auto alloc = [&](size_t bytes)->char*{
        char* p = ws + off;
        off = (off + bytes + 255) & ~(size_t)255;
        return p;
    };
    int nb = (N + 255) / 256;                   // scan blocks (N<=32768)
    int MP = N + 128;                           // row-padded for OOB tile staging
    int*   cnt  = (int*)  alloc((size_t)N*4);
    int*   incl = (int*)  alloc((size_t)N*4);
    int*   bsum = (int*)  alloc(512);
    int*   efmt = (int*)  alloc(4);
    float* dis  = (float*)alloc((size_t)N*4);
    int*   rs   = (int*)  alloc((size_t)(N+1)*4);
    int*   cur  = (int*)  alloc((size_t)N*4);
    int*   csr  = (int*)  alloc((size_t)E*4);
    u16*   WT1  = (u16*)  alloc((size_t)512*512*2);
    u16*   WT2  = (u16*)  alloc((size_t)256*512*2);
    u16*   WT3  = (u16*)  alloc((size_t)256*256*2);
    u16*   WT4  = (u16*)  alloc((size_t)256*256*2);
    u16*   b1c  = (u16*)  alloc((size_t)512*2);
    u16*   b2c  = (u16*)  alloc((size_t)256*2);
    u16*   b3c  = (u16*)  alloc((size_t)256*2);
    u16*   b4c  = (u16*)  alloc((size_t)256*2);
    u16*   ac   = (u16*)  alloc((size_t)8*2);
    u16*   Xbf  = (u16*)  alloc((size_t)MP*512*2);  // 20.6 MB
    u16*   h1   = (u16*)  alloc((size_t)MP*512*2);  // 20.6 MB
    u16*   P    = (u16*)  alloc((size_t)MP*256*2);  // 10.3 MB

    if (ws_size < off) return;

    probe_all<<<1, 256, 0, stream>>>((const u16*)d_in[iW1], EI,
                                     d_in[ib1], d_in[ib2], d_in[ib3], d_in[ib4],
                                     d_in[ia], efmt, cnt, N,
                                     b1c, b2c, b3c, b4c, ac);

    transpose_x<<<dim3(16, 16, 5), dim3(32, 8), 0, stream>>>(
        d_in[iW1], d_in[iW2], d_in[iW3], d_in[iW4], d_in[iX],
        WT1, WT2, WT3, WT4, Xbf, N);

    int egrid = (E + 255) / 256;
    deg_count<<<egrid, 256, 0, stream>>>(EI, efmt, cnt, E, N);
    scan1<<<nb, 256, 0, stream>>>(cnt, incl, bsum, N);
    scan23<<<nb, 256, 0, stream>>>(cnt, incl, bsum, nb, rs, cur, dis, N);
    csr_fill<<<egrid, 256, 0, stream>>>(EI, efmt, cur, csr, E, N);

    int gm = (N + GTM - 1) / GTM;         // 157
    int nodeb = (N + 31) / 32;            // 625

    // layer 1: Xbf @ W1 -> S (bf16 scratch in OUT buffer), aggregate -> h1
    gemm128<0,0><<<gm*4, 256, 0, stream>>>(Xbf, WT1, nullptr, S, N, 512, 512, 4);
    aggregate_ch<512,64><<<nodeb*8, 256, 0, stream>>>(S, rs, csr, dis, b1c, ac, h1, N);

    // layer 2: h1 @ W2 -> P ; aggregate -> Q (OUT bytes as bf16; S dead)
    u16* Q = (u16*)d_out;
    gemm128<0,0><<<gm*2, 256, 0, stream>>>(h1, WT2, nullptr, P, N, 512, 256, 2);
    aggregate_ch<256,64><<<nodeb*4, 256, 0, stream>>>(P, rs, csr, dis, b2c, ac, Q, N);

    // projection MLP: ELU(Q @ W3 + b3) -> P ; P @ W4 + b4 -> OUT (fp32)
    gemm128<2,0><<<gm*2, 256, 0, stream>>>(Q, WT3, b3c, P, N, 256, 256, 2);
    gemm128<1,1><<<gm*2, 256, 0, stream>>>(P, WT4, b4c, OUT, N, 256, 256, 2);
}